// Round 1
// 68.574 us; speedup vs baseline: 1.0781x; 1.0781x over previous
//
#include <hip/hip_runtime.h>
#include <math.h>

// Problem constants (from reference): LMAX=8, BVALS={1,2,3}
#define FF 3          // fibers per voxel
#define BB 3          // b-values
#define KK 45         // SH terms for even l in [0,8]
#define VOX 8         // voxels per block
#define TPB 256
#define NT 18         // Taylor terms for I_l(a), |a| <= 3
#define NFIB (VOX*FF)         // 24 fiber tasks / block
#define NRHO (VOX*FF*BB)      // 72 rho tasks / block

// ---------------- constexpr helpers ----------------
constexpr double csqrt(double x) {
    double g = x > 1.0 ? x : 1.0;
    for (int i = 0; i < 64; ++i) g = 0.5 * (g + x / g);
    return g;
}

// I_l(a) = int_0^1 exp(-a t^2) P_l(t) dt  (even l) = sum_k d[l/2][k] a^k
struct Tab { float d[5][NT]; };
constexpr Tab make_tab() {
    Tab t{};
    for (int li = 0; li < 5; ++li) {
        const int l = 2 * li;
        double kfact = 1.0;
        for (int k = 0; k < NT; ++k) {
            if (k > 0) kfact *= (double)k;
            double c = 0.0;
            if (2 * k >= l) {
                double num = 1.0, den = 1.0;
                for (int j = 0; j < l / 2; ++j)  num *= (double)(2 * k - 2 * j);
                for (int j = 0; j <= l / 2; ++j) den *= (double)(2 * k + 1 + 2 * j);
                c = num / den;
            }
            t.d[li][k] = (float)(((k & 1) ? -1.0 : 1.0) * c / kfact);
        }
    }
    return t;
}
static constexpr Tab HOST_TAB = make_tab();
__constant__ Tab TAB = HOST_TAB;

// per-k tables (used only with compile-time indices -> folds to immediates)
struct KTab {
    float nrm[KK];
    unsigned char lidx[KK];
    unsigned char ma[KK];
    unsigned char neg[KK];
};
constexpr KTab make_ktab() {
    KTab t{};
    int k = 0;
    for (int l = 0; l <= 8; l += 2) {
        for (int m = -l; m <= l; ++m, ++k) {
            const int ma = m < 0 ? -m : m;
            double prod = 1.0;
            for (int i = l - ma + 1; i <= l + ma; ++i) prod *= (double)i;
            double nrm = csqrt((double)(2 * l + 1) * 0.07957747154594767 / prod);
            if (m != 0) nrm *= csqrt(2.0);
            t.nrm[k]  = (float)nrm;
            t.lidx[k] = (unsigned char)(l / 2);
            t.ma[k]   = (unsigned char)ma;
            t.neg[k]  = (unsigned char)(m < 0 ? 1 : 0);
        }
    }
    return t;
}
static constexpr KTab HKT = make_ktab();

// fused per-r table for outS: r in [0,135) = bi*45 + k
//   low byte : bi*5 + lidx(k)   (offset into wrho row, max 14)
//   high byte: k                (offset into sh row)
struct STab { unsigned short v[BB * KK]; };
constexpr STab make_stab() {
    STab t{};
    KTab kt = make_ktab();
    for (int r = 0; r < BB * KK; ++r) {
        const int bi = r / KK;
        const int k  = r % KK;
        t.v[r] = (unsigned short)((unsigned)(bi * 5 + kt.lidx[k]) | ((unsigned)k << 8));
    }
    return t;
}
static constexpr STab HOST_STAB = make_stab();
__constant__ STab TS = HOST_STAB;

__device__ __forceinline__ void eval_I(float a, float I[5]) {
    #pragma unroll
    for (int li = 0; li < 5; ++li) {
        float acc = TAB.d[li][NT - 1];
        #pragma unroll
        for (int k = NT - 2; k >= 0; --k)
            acc = fmaf(acc, a, TAB.d[li][k]);
        I[li] = acc;
    }
}

__global__ __launch_bounds__(TPB) void fused_sim_kernel(
    const float* __restrict__ directs,   // (N,F,3)
    const float* __restrict__ weights,   // (N,F)
    const float* __restrict__ shapes,    // (N,F,4): D_a, D_epar, D_eperp, z
    const int*   __restrict__ num_t_p,   // scalar
    float* __restrict__ outS,            // (N,B,K)
    float* __restrict__ outODF,          // (N,F,K)
    float* __restrict__ outEig,          // (N,B,F,K)
    int N)
{
    const int n0  = blockIdx.x * VOX;
    const int tid = threadIdx.x;
    const bool full = (n0 + VOX <= N);

    __shared__ __align__(16) float sh_s[NFIB * KK];            // 1080: (v,f,k)
    __shared__ __align__(16) float eig_s[VOX * BB * FF * KK];  // 3240: (v,bi,f,k)
    __shared__ __align__(16) float wrho_s[NRHO * 5];           // 360:  (v,f,bi,li)

    // ---- Phase 1a (wave 0, lanes 0..23): per-fiber SH, fully in registers ----
    if (tid < NFIB) {
        const int f = tid % FF;
        const int n = n0 + tid / FF;
        if (n < N) {
            const float dx = directs[(n * FF + f) * 3 + 0];
            const float dy = directs[(n * FF + f) * 3 + 1];
            const float dz = directs[(n * FF + f) * 3 + 2];
            const float inv = 1.0f / sqrtf(dx * dx + dy * dy + dz * dz);
            const float x = dx * inv, y = dy * inv, z = dz * inv;
            float s2 = 1.0f - z * z;
            s2 = fminf(fmaxf(s2, 0.0f), 1.0f);
            const float s = sqrtf(s2);

            const float rxy2 = x * x + y * y;
            float cphi = 1.0f, sphi = 0.0f;
            if (rxy2 > 0.0f) {
                const float ir = 1.0f / sqrtf(rxy2);
                cphi = x * ir;
                sphi = y * ir;
            }

            // trig recurrence -> registers
            float cmv[9], smv[9];
            float cm = 1.0f, sm = 0.0f;
            #pragma unroll
            for (int m = 0; m <= 8; ++m) {
                cmv[m] = cm;
                smv[m] = sm;
                const float cn = cm * cphi - sm * sphi;
                const float sn = sm * cphi + cm * sphi;
                cm = cn; sm = sn;
            }

            // associated Legendre (even l) -> registers; idx = (l/2)^2 + ma
            float Preg[25];
            float pmm = 1.0f;
            #pragma unroll
            for (int ma = 0; ma <= 8; ++ma) {
                if (ma > 0) pmm *= -(float)(2 * ma - 1) * s;
                if ((ma & 1) == 0)
                    Preg[(ma / 2) * (ma / 2) + ma] = pmm;
                float pa = pmm;
                float pb = (float)(2 * ma + 1) * z * pa;   // P(ma+1,ma)
                if (ma + 1 <= 8 && ((ma + 1) & 1) == 0)
                    Preg[((ma + 1) / 2) * ((ma + 1) / 2) + ma] = pb;
                #pragma unroll
                for (int ll = ma + 2; ll <= 8; ++ll) {
                    const float invd = 1.0f / (float)(ll - ma);
                    const float pn = ((float)(2 * ll - 1) * z * pb
                                      - (float)(ll + ma - 1) * pa) * invd;
                    pa = pb; pb = pn;
                    if ((ll & 1) == 0)
                        Preg[(ll / 2) * (ll / 2) + ma] = pn;
                }
            }

            // all 45 SH values; indices/norms are compile-time constants
            float* shrow = sh_s + tid * KK;
            #pragma unroll
            for (int k = 0; k < KK; ++k) {
                const int   lidx = HKT.lidx[k];
                const int   ma   = HKT.ma[k];
                const float tr   = HKT.neg[k] ? smv[ma] : cmv[ma];
                shrow[k] = HKT.nrm[k] * tr * Preg[lidx * lidx + ma];
            }
        }
    }

    // ---- Phase 1b (waves 1-2, tids 64..135): rho + eig expansion + w*rho ----
    if (tid >= 64 && tid < 64 + NRHO) {
        const int w  = tid - 64;          // (v*FF + f)*BB + bi
        const int fi = w / BB;
        const int bi = w % BB;
        const int v  = fi / FF;
        const int f  = fi % FF;
        const int n  = n0 + v;
        if (n < N) {
            const float bval = (float)(bi + 1);              // BVALS = {1,2,3}

            const float4 sp4 = *(const float4*)(shapes + (size_t)(n * FF + f) * 4);
            const float D_a     = sp4.x;
            const float D_epar  = sp4.y;
            const float D_eperp = sp4.z;
            const float zf      = sp4.w;

            const float bA = bval * D_a;
            const float bE = bval * (D_epar - D_eperp);
            const float zc = (1.0f - zf) * __expf(-bval * D_eperp);

            const float T     = (float)num_t_p[0];
            const float h     = 1.0f / (T - 1.0f);
            const float scale = (T - 1.0f) / T;
            const float h212  = h * h * (1.0f / 12.0f);

            float IA[5], IE[5];
            eval_I(bA, IA);
            eval_I(bE, IE);
            const float eA = __expf(-bA);
            const float eE = __expf(-bE);

            float rho[5];
            #pragma unroll
            for (int li = 0; li < 5; ++li) {
                const int   l   = 2 * li;
                const float pl1 = 0.5f * (float)(l * (l + 1));
                const float QA = IA[li] + h212 * eA * (pl1 - 2.0f * bA);
                const float QE = IE[li] + h212 * eE * (pl1 - 2.0f * bE);
                rho[li] = scale * (zf * QA + zc * QE);
            }

            const float wt = weights[n * FF + f];
            #pragma unroll
            for (int li = 0; li < 5; ++li)
                wrho_s[w * 5 + li] = wt * rho[li];

            // eigen row in output order (v, bi, f, k); lidx[k] folds -> reg select
            float* er = eig_s + (v * (BB * FF) + bi * FF + f) * KK;
            #pragma unroll
            for (int k = 0; k < KK; ++k)
                er[k] = rho[HKT.lidx[k]];
        }
    }

    __syncthreads();

    // ---- Phase 2a: outEig = pure linear float4 copy (810 quads) ----
    {
        float4* dst = (float4*)(outEig + (size_t)n0 * (BB * FF * KK));
        const float4* src = (const float4*)eig_s;
        if (full) {
            for (int q = tid; q < VOX * BB * FF * KK / 4; q += TPB)
                dst[q] = src[q];
        } else {
            for (int e = tid; e < VOX * BB * FF * KK; e += TPB)
                if (n0 + e / (BB * FF * KK) < N)
                    outEig[(size_t)n0 * (BB * FF * KK) + e] = eig_s[e];
        }
    }

    // ---- Phase 2b: outODF = pure linear float4 copy (270 quads) ----
    {
        float4* dst = (float4*)(outODF + (size_t)n0 * (FF * KK));
        const float4* src = (const float4*)sh_s;
        if (full) {
            for (int q = tid; q < VOX * FF * KK / 4; q += TPB)
                dst[q] = src[q];
        } else {
            for (int e = tid; e < VOX * FF * KK; e += TPB)
                if (n0 + e / (FF * KK) < N)
                    outODF[(size_t)n0 * (FF * KK) + e] = sh_s[e];
        }
    }

    // ---- Phase 2c: outS (270 quads), one div per quad + fused u16 table ----
    {
        float4* dst = (float4*)(outS + (size_t)n0 * (BB * KK));
        for (int q = tid; q < VOX * BB * KK / 4; q += TPB) {
            const int e0 = 4 * q;
            int vv = (int)((unsigned)e0 / (unsigned)(BB * KK));
            int r  = e0 - vv * (BB * KK);
            const float* wrb = wrho_s + vv * (FF * BB * 5);  // + f*15 + (bi*5+lidx)
            const float* shb = sh_s   + vv * (FF * KK);      // + f*45 + k
            float4 out;
            float* oc = &out.x;
            #pragma unroll
            for (int j = 0; j < 4; ++j) {
                if (r >= BB * KK) { r -= BB * KK; wrb += FF * BB * 5; shb += FF * KK; }
                const unsigned ts = TS.v[r];
                const float* wr = wrb + (ts & 0xffu);
                const float* sp = shb + (ts >> 8);
                float ssum = 0.0f;
                ssum = fmaf(wr[0],  sp[0],  ssum);   // f = 0
                ssum = fmaf(wr[15], sp[45], ssum);   // f = 1
                ssum = fmaf(wr[30], sp[90], ssum);   // f = 2
                oc[j] = ssum;
                ++r;
            }
            if (full) {
                dst[q] = out;
            } else {
                #pragma unroll
                for (int j = 0; j < 4; ++j) {
                    const int e = 4 * q + j;
                    if (n0 + e / (BB * KK) < N)
                        outS[(size_t)n0 * (BB * KK) + e] = oc[j];
                }
            }
        }
    }
}

extern "C" void kernel_launch(void* const* d_in, const int* in_sizes, int n_in,
                              void* d_out, int out_size, void* d_ws, size_t ws_size,
                              hipStream_t stream) {
    const float* directs = (const float*)d_in[0];   // (N,F,3)
    const float* weights = (const float*)d_in[1];   // (N,F)
    const float* shapes  = (const float*)d_in[2];   // (N,F,4)
    const int*   num_t   = (const int*)d_in[3];     // scalar

    const int N = in_sizes[0] / (FF * 3);

    float* outS   = (float*)d_out;                        // N*BB*KK
    float* outODF = outS + (size_t)N * BB * KK;           // N*FF*KK
    float* outEig = outODF + (size_t)N * FF * KK;         // N*BB*FF*KK

    const int blocks = (N + VOX - 1) / VOX;
    fused_sim_kernel<<<blocks, TPB, 0, stream>>>(directs, weights, shapes, num_t,
                                                 outS, outODF, outEig, N);
}